// Round 1
// baseline (99.460 us; speedup 1.0000x reference)
//
#include <hip/hip_runtime.h>
#include <hip/hip_bf16.h>

#define B_SZ   1024
#define NIN    64
#define NOUT   4096
#define NBATCH 64
#define NCONT  16
#define LTOT   80      // NIN + NCONT fused reduction length
#define GCHUNK 256     // g-values per block (== threads)
#define TS     16      // sample tile

// ---------------------------------------------------------------------------
// Kernel 1: h[c,g] = sum_l z[c,l]*(amat_W[l,g] + embed_A[b, g*64+l])
//                  + sum_k cont[c,k]*cont_W[k,g] + embed_h3[b,g]
// grouped by batch b so embed_A is streamed from HBM exactly once.
// grid = (16 g-chunks, 64 batches), 256 threads; thread owns one g column.
// ---------------------------------------------------------------------------
__global__ __launch_bounds__(256) void k_h(
    const float* __restrict__ z,
    const int*   __restrict__ idx,
    const float* __restrict__ cont,
    const float* __restrict__ amat_W,
    const float* __restrict__ embed_A,
    const float* __restrict__ embed_h3,
    const float* __restrict__ cont_W,
    float*       __restrict__ hout)
{
    const int gc  = blockIdx.x;            // 0..15
    const int b   = blockIdx.y;            // 0..63
    const int tid = threadIdx.x;
    const int g0  = gc * GCHUNK;
    const int g   = g0 + tid;

    __shared__ int   s_cnt;
    __shared__ int   s_list[B_SZ];         // 4 KB
    __shared__ float s_x[TS][LTOT];        // 5 KB

    // ---- build list of samples with idx[c] == b (order-independent output)
    if (tid == 0) s_cnt = 0;
    __syncthreads();
    for (int c = tid; c < B_SZ; c += 256) {
        if (idx[c] == b) {
            int p = atomicAdd(&s_cnt, 1);
            s_list[p] = c;
        }
    }
    __syncthreads();
    const int cnt = s_cnt;

    // ---- fused M column (80 floats) in registers
    float M[LTOT];
    #pragma unroll
    for (int l = 0; l < NIN; ++l)
        M[l] = amat_W[l * NOUT + g];                       // coalesced

    const float4* a4 = reinterpret_cast<const float4*>(
        embed_A + (size_t)b * (NOUT * NIN) + (size_t)g * NIN);
    #pragma unroll
    for (int q = 0; q < NIN / 4; ++q) {                    // thread-contiguous
        float4 v = a4[q];
        M[4*q + 0] += v.x; M[4*q + 1] += v.y;
        M[4*q + 2] += v.z; M[4*q + 3] += v.w;
    }
    #pragma unroll
    for (int k = 0; k < NCONT; ++k)
        M[NIN + k] = cont_W[k * NOUT + g];                 // coalesced

    const float h3v = embed_h3[b * NOUT + g];

    // ---- sample tiles
    for (int s0 = 0; s0 < cnt; s0 += TS) {
        const int ns = min(TS, cnt - s0);

        // stage X = [z | cont] for this tile, zero-fill unused slots
        for (int i = tid; i < TS * LTOT; i += 256) {
            const int t = i / LTOT;
            const int l = i - t * LTOT;
            float v = 0.f;
            if (t < ns) {
                const int c = s_list[s0 + t];
                v = (l < NIN) ? z[c * NIN + l]
                              : cont[c * NCONT + (l - NIN)];
            }
            s_x[t][l] = v;
        }
        __syncthreads();

        float acc[TS];
        #pragma unroll
        for (int t = 0; t < TS; ++t) acc[t] = 0.f;

        #pragma unroll
        for (int l4 = 0; l4 < LTOT / 4; ++l4) {
            #pragma unroll
            for (int t = 0; t < TS; ++t) {
                const float4 x = *reinterpret_cast<const float4*>(&s_x[t][l4 * 4]);
                acc[t] += x.x * M[4*l4 + 0] + x.y * M[4*l4 + 1]
                        + x.z * M[4*l4 + 2] + x.w * M[4*l4 + 3];
            }
        }

        for (int t = 0; t < ns; ++t) {
            const int c = s_list[s0 + t];
            hout[(size_t)c * NOUT + g] = acc[t] + h3v;     // coalesced
        }
        __syncthreads();   // before next tile overwrites s_x
    }
}

// ---------------------------------------------------------------------------
// Kernel 2: in-place row softmax * size_factor; blocks 0..15 also write
// inverse_dispersion = exp(px_r).
// grid = 1024 rows, 256 threads; row (4096 f) held in registers.
// ---------------------------------------------------------------------------
__global__ __launch_bounds__(256) void k_softmax(
    float*       __restrict__ out,
    const float* __restrict__ sf,
    const float* __restrict__ px_r)
{
    const int c   = blockIdx.x;
    const int tid = threadIdx.x;
    float4* row4 = reinterpret_cast<float4*>(out + (size_t)c * NOUT);

    float4 v[4];
    #pragma unroll
    for (int j = 0; j < 4; ++j) v[j] = row4[j * 256 + tid];

    float m = -3.4e38f;
    #pragma unroll
    for (int j = 0; j < 4; ++j)
        m = fmaxf(fmaxf(fmaxf(m, v[j].x), fmaxf(v[j].y, v[j].z)), v[j].w);

    #pragma unroll
    for (int off = 32; off > 0; off >>= 1)
        m = fmaxf(m, __shfl_xor(m, off, 64));

    __shared__ float s_red[8];
    const int wave = tid >> 6;
    const int lane = tid & 63;
    if (lane == 0) s_red[wave] = m;
    __syncthreads();
    m = fmaxf(fmaxf(s_red[0], s_red[1]), fmaxf(s_red[2], s_red[3]));

    float s = 0.f;
    #pragma unroll
    for (int j = 0; j < 4; ++j) {
        v[j].x = __expf(v[j].x - m); v[j].y = __expf(v[j].y - m);
        v[j].z = __expf(v[j].z - m); v[j].w = __expf(v[j].w - m);
        s += v[j].x + v[j].y + v[j].z + v[j].w;
    }
    #pragma unroll
    for (int off = 32; off > 0; off >>= 1)
        s += __shfl_xor(s, off, 64);
    if (lane == 0) s_red[4 + wave] = s;
    __syncthreads();
    s = s_red[4] + s_red[5] + s_red[6] + s_red[7];

    const float scale = sf[c] / s;
    #pragma unroll
    for (int j = 0; j < 4; ++j) {
        v[j].x *= scale; v[j].y *= scale; v[j].z *= scale; v[j].w *= scale;
        row4[j * 256 + tid] = v[j];
    }

    if (c < NOUT / 256) {                 // 16 blocks cover px_r
        const int i = c * 256 + tid;
        out[(size_t)B_SZ * NOUT + i] = __expf(px_r[i]);
    }
}

// ---------------------------------------------------------------------------
extern "C" void kernel_launch(void* const* d_in, const int* in_sizes, int n_in,
                              void* d_out, int out_size, void* d_ws, size_t ws_size,
                              hipStream_t stream)
{
    const float* z       = (const float*)d_in[0];
    const int*   idx     = (const int*)  d_in[1];
    const float* sf      = (const float*)d_in[2];
    const float* cont    = (const float*)d_in[3];
    const float* amat_W  = (const float*)d_in[4];
    const float* embed_A = (const float*)d_in[5];
    const float* eh3     = (const float*)d_in[6];
    const float* cont_W  = (const float*)d_in[7];
    const float* px_r    = (const float*)d_in[8];
    float* out = (float*)d_out;

    dim3 grid1(NOUT / GCHUNK, NBATCH);    // (16, 64)
    k_h<<<grid1, 256, 0, stream>>>(z, idx, cont, amat_W, embed_A, eh3, cont_W, out);

    k_softmax<<<B_SZ, 256, 0, stream>>>(out, sf, px_r);
}

// Round 2
// 61.185 us; speedup vs baseline: 1.6255x; 1.6255x over previous
//
#include <hip/hip_runtime.h>
#include <hip/hip_bf16.h>

#define B_SZ   1024
#define NIN    64
#define NOUT   4096
#define NBATCH 64
#define NCONT  16
#define LTOT   80      // NIN + NCONT fused reduction length
#define GCHUNK 256     // g-values per block (== threads)

// ---------------------------------------------------------------------------
// Kernel 1: h[c,g] = sum_l z[c,l]*(amat_W[l,g] + embed_A[b, g*64+l])
//                  + sum_k cont[c,k]*cont_W[k,g] + embed_h3[b,g]
// grouped by batch b so embed_A is streamed from HBM/L3 exactly once.
// X rows are wave-uniform -> scalar (SGPR) loads, inner loop is pure
// v_fma_f32 with one SGPR operand. No LDS in the hot loop.
// grid = (16 g-chunks, 64 batches), 256 threads; thread owns one g column.
// ---------------------------------------------------------------------------
__global__ __launch_bounds__(256, 4) void k_h(
    const float* __restrict__ z,
    const int*   __restrict__ idx,
    const float* __restrict__ cont,
    const float* __restrict__ amat_W,
    const float* __restrict__ embed_A,
    const float* __restrict__ embed_h3,
    const float* __restrict__ cont_W,
    float*       __restrict__ hout)
{
    const int gc  = blockIdx.x;            // 0..15
    const int b   = blockIdx.y;            // 0..63
    const int tid = threadIdx.x;
    const int g   = gc * GCHUNK + tid;

    __shared__ int s_cnt;
    __shared__ int s_list[B_SZ];           // 4 KB

    if (tid == 0) s_cnt = 0;
    __syncthreads();
    for (int c = tid; c < B_SZ; c += 256) {
        if (idx[c] == b) {
            int p = atomicAdd(&s_cnt, 1);
            s_list[p] = c;
        }
    }
    __syncthreads();
    const int cnt = s_cnt;

    // ---- fused M column (80 floats) in registers
    float M[LTOT];
    #pragma unroll
    for (int l = 0; l < NIN; ++l)
        M[l] = amat_W[l * NOUT + g];                       // coalesced

    const float4* a4 = reinterpret_cast<const float4*>(
        embed_A + (size_t)b * (NOUT * NIN) + (size_t)g * NIN);
    #pragma unroll
    for (int q = 0; q < NIN / 4; ++q) {                    // thread-contiguous
        float4 v = a4[q];
        M[4*q + 0] += v.x; M[4*q + 1] += v.y;
        M[4*q + 2] += v.z; M[4*q + 3] += v.w;
    }
    #pragma unroll
    for (int k = 0; k < NCONT; ++k)
        M[NIN + k] = cont_W[k * NOUT + g];                 // coalesced

    const float h3v = embed_h3[b * NOUT + g];

    // ---- samples, 2-way unrolled for scalar-load ILP
    int s = 0;
    for (; s + 2 <= cnt; s += 2) {
        const int c0 = __builtin_amdgcn_readfirstlane(s_list[s]);
        const int c1 = __builtin_amdgcn_readfirstlane(s_list[s + 1]);
        const float* __restrict__ x0 = z + c0 * NIN;
        const float* __restrict__ x1 = z + c1 * NIN;
        const float* __restrict__ q0 = cont + c0 * NCONT;
        const float* __restrict__ q1 = cont + c1 * NCONT;
        float a0 = h3v, a1 = h3v;
        #pragma unroll
        for (int l = 0; l < NIN; ++l) {
            a0 = fmaf(x0[l], M[l], a0);
            a1 = fmaf(x1[l], M[l], a1);
        }
        #pragma unroll
        for (int k = 0; k < NCONT; ++k) {
            a0 = fmaf(q0[k], M[NIN + k], a0);
            a1 = fmaf(q1[k], M[NIN + k], a1);
        }
        hout[(size_t)c0 * NOUT + g] = a0;                  // coalesced
        hout[(size_t)c1 * NOUT + g] = a1;
    }
    if (s < cnt) {
        const int c0 = __builtin_amdgcn_readfirstlane(s_list[s]);
        const float* __restrict__ x0 = z + c0 * NIN;
        const float* __restrict__ q0 = cont + c0 * NCONT;
        float a0 = h3v;
        #pragma unroll
        for (int l = 0; l < NIN; ++l) a0 = fmaf(x0[l], M[l], a0);
        #pragma unroll
        for (int k = 0; k < NCONT; ++k) a0 = fmaf(q0[k], M[NIN + k], a0);
        hout[(size_t)c0 * NOUT + g] = a0;
    }
}

// ---------------------------------------------------------------------------
// Kernel 2: in-place row softmax * size_factor; blocks 0..15 also write
// inverse_dispersion = exp(px_r).
// grid = 1024 rows, 256 threads; row (4096 f) held in registers.
// ---------------------------------------------------------------------------
__global__ __launch_bounds__(256) void k_softmax(
    float*       __restrict__ out,
    const float* __restrict__ sf,
    const float* __restrict__ px_r)
{
    const int c   = blockIdx.x;
    const int tid = threadIdx.x;
    float4* row4 = reinterpret_cast<float4*>(out + (size_t)c * NOUT);

    float4 v[4];
    #pragma unroll
    for (int j = 0; j < 4; ++j) v[j] = row4[j * 256 + tid];

    float m = -3.4e38f;
    #pragma unroll
    for (int j = 0; j < 4; ++j)
        m = fmaxf(fmaxf(fmaxf(m, v[j].x), fmaxf(v[j].y, v[j].z)), v[j].w);

    #pragma unroll
    for (int off = 32; off > 0; off >>= 1)
        m = fmaxf(m, __shfl_xor(m, off, 64));

    __shared__ float s_red[8];
    const int wave = tid >> 6;
    const int lane = tid & 63;
    if (lane == 0) s_red[wave] = m;
    __syncthreads();
    m = fmaxf(fmaxf(s_red[0], s_red[1]), fmaxf(s_red[2], s_red[3]));

    float s = 0.f;
    #pragma unroll
    for (int j = 0; j < 4; ++j) {
        v[j].x = __expf(v[j].x - m); v[j].y = __expf(v[j].y - m);
        v[j].z = __expf(v[j].z - m); v[j].w = __expf(v[j].w - m);
        s += v[j].x + v[j].y + v[j].z + v[j].w;
    }
    #pragma unroll
    for (int off = 32; off > 0; off >>= 1)
        s += __shfl_xor(s, off, 64);
    if (lane == 0) s_red[4 + wave] = s;
    __syncthreads();
    s = s_red[4] + s_red[5] + s_red[6] + s_red[7];

    const float scale = sf[c] / s;
    #pragma unroll
    for (int j = 0; j < 4; ++j) {
        v[j].x *= scale; v[j].y *= scale; v[j].z *= scale; v[j].w *= scale;
        row4[j * 256 + tid] = v[j];
    }

    if (c < NOUT / 256) {                 // 16 blocks cover px_r
        const int i = c * 256 + tid;
        out[(size_t)B_SZ * NOUT + i] = __expf(px_r[i]);
    }
}

// ---------------------------------------------------------------------------
extern "C" void kernel_launch(void* const* d_in, const int* in_sizes, int n_in,
                              void* d_out, int out_size, void* d_ws, size_t ws_size,
                              hipStream_t stream)
{
    const float* z       = (const float*)d_in[0];
    const int*   idx     = (const int*)  d_in[1];
    const float* sf      = (const float*)d_in[2];
    const float* cont    = (const float*)d_in[3];
    const float* amat_W  = (const float*)d_in[4];
    const float* embed_A = (const float*)d_in[5];
    const float* eh3     = (const float*)d_in[6];
    const float* cont_W  = (const float*)d_in[7];
    const float* px_r    = (const float*)d_in[8];
    float* out = (float*)d_out;

    dim3 grid1(NOUT / GCHUNK, NBATCH);    // (16, 64)
    k_h<<<grid1, 256, 0, stream>>>(z, idx, cont, amat_W, embed_A, eh3, cont_W, out);

    k_softmax<<<B_SZ, 256, 0, stream>>>(out, sf, px_r);
}